// Round 4
// baseline (355.843 us; speedup 1.0000x reference)
//
#include <hip/hip_runtime.h>
#include <hip/hip_bf16.h>
#include <math.h>

#define B_ 8
#define N_ 256
#define H_ 128
#define NODES_ (B_ * N_)   // 2048

typedef float vf2 __attribute__((ext_vector_type(2)));

__device__ __forceinline__ float silu_fast(float x) {
    float e = __expf(-x);
    return x * __builtin_amdgcn_rcpf(1.0f + e);
}

// K=128 column-GEMM inner: thread owns 4 output columns (c0..c0+3), weights
// at Wc (already offset by c0, row stride H_), activations arow[] in LDS
// (wave-broadcast reads). float4 weight loads, 8-deep ping-pong pipeline.
__device__ __forceinline__ float4 colgemm128(const float* __restrict__ Wc,
                                             const float* __restrict__ arow)
{
    float4 wA[8], wB[8];
    #pragma unroll
    for (int u = 0; u < 8; ++u) wA[u] = *(const float4*)(Wc + u * H_);
    float4 a = {0.f,0.f,0.f,0.f}, b = {0.f,0.f,0.f,0.f};
    #pragma unroll
    for (int k = 0; k < 128; k += 16) {
        #pragma unroll
        for (int u = 0; u < 8; ++u) wB[u] = *(const float4*)(Wc + (k + 8 + u) * H_);
        #pragma unroll
        for (int u = 0; u < 8; u += 2) {
            float v0 = arow[k + u], v1 = arow[k + u + 1];
            a.x = fmaf(v0, wA[u].x, a.x);   a.y = fmaf(v0, wA[u].y, a.y);
            a.z = fmaf(v0, wA[u].z, a.z);   a.w = fmaf(v0, wA[u].w, a.w);
            b.x = fmaf(v1, wA[u+1].x, b.x); b.y = fmaf(v1, wA[u+1].y, b.y);
            b.z = fmaf(v1, wA[u+1].z, b.z); b.w = fmaf(v1, wA[u+1].w, b.w);
        }
        if (k + 16 < 128) {
            #pragma unroll
            for (int u = 0; u < 8; ++u) wA[u] = *(const float4*)(Wc + (k + 16 + u) * H_);
        }
        #pragma unroll
        for (int u = 0; u < 8; u += 2) {
            float v0 = arow[k + 8 + u], v1 = arow[k + 8 + u + 1];
            a.x = fmaf(v0, wB[u].x, a.x);   a.y = fmaf(v0, wB[u].y, a.y);
            a.z = fmaf(v0, wB[u].z, a.z);   a.w = fmaf(v0, wB[u].w, a.w);
            b.x = fmaf(v1, wB[u+1].x, b.x); b.y = fmaf(v1, wB[u+1].y, b.y);
            b.z = fmaf(v1, wB[u+1].z, b.z); b.w = fmaf(v1, wB[u+1].w, b.w);
        }
    }
    float4 r; r.x = a.x + b.x; r.y = a.y + b.y; r.z = a.z + b.z; r.w = a.w + b.w;
    return r;
}

// Scalar variant (one column/thread) for k0.
__device__ __forceinline__ float colgemm128_s(const float* __restrict__ Wc,
                                              const float* __restrict__ arow)
{
    float wA[8], wB[8];
    #pragma unroll
    for (int u = 0; u < 8; ++u) wA[u] = Wc[u * H_];
    float a = 0.f, b = 0.f;
    #pragma unroll
    for (int k = 0; k < 128; k += 16) {
        #pragma unroll
        for (int u = 0; u < 8; ++u) wB[u] = Wc[(k + 8 + u) * H_];
        #pragma unroll
        for (int u = 0; u < 8; u += 2) {
            a = fmaf(arow[k + u],     wA[u],     a);
            b = fmaf(arow[k + u + 1], wA[u + 1], b);
        }
        if (k + 16 < 128) {
            #pragma unroll
            for (int u = 0; u < 8; ++u) wA[u] = Wc[(k + 16 + u) * H_];
        }
        #pragma unroll
        for (int u = 0; u < 8; u += 2) {
            a = fmaf(arow[k + 8 + u],     wB[u],     a);
            b = fmaf(arow[k + 8 + u + 1], wB[u + 1], b);
        }
    }
    return a + b;
}

// ---------------------------------------------------------------------------
// k0: W'[r][c] = sum_l We2[r][l]*Wn1[128+l][c]  (blocks 0..127, row r)
//     b'[c]    = sum_l be2[l]  *Wn1[128+l][c]  (block 128)
// ---------------------------------------------------------------------------
__global__ __launch_bounds__(128) void k0_fold(
    const float* __restrict__ We2, const float* __restrict__ be2,
    const float* __restrict__ Wn1, float* __restrict__ Wp, float* __restrict__ bp)
{
    __shared__ float arow[128];
    const int t = threadIdx.x;
    const int r = blockIdx.x;
    arow[t] = (r < 128) ? We2[r * H_ + t] : be2[t];
    __syncthreads();
    float acc = colgemm128_s(Wn1 + 128 * H_ + t, arow);
    if (r < 128) Wp[r * H_ + t] = acc;
    else         bp[t] = acc;
}

// ---------------------------------------------------------------------------
// k1: P = node@We1a + be1 ; Q = node@We1b + (m-1)*1e30 (mask folded -> silu=0)
//     pre = node@Wn1a + bn1
// grid 3*512 (4-node tiles), block 128: n=t>>5, c0=(t&31)*4.
// ---------------------------------------------------------------------------
__global__ __launch_bounds__(128, 3) void k1(
    const float* __restrict__ node, const float* __restrict__ We1,
    const float* __restrict__ be1, const float* __restrict__ Wn1,
    const float* __restrict__ bn1, const float* __restrict__ mask,
    float* __restrict__ P, float* __restrict__ Q, float* __restrict__ pre)
{
    __shared__ float act[4][128];
    const int t = threadIdx.x;
    const int g = blockIdx.x >> 9;               // 0:P 1:Q 2:pre
    const int node0 = (blockIdx.x & 511) * 4;
    {
        int r = t >> 5, col = (t * 4) & 127;
        *(float4*)(&act[r][col]) = *(const float4*)(node + (size_t)(node0 + r) * H_ + col);
    }
    const float* W; float* op;
    if (g == 0)      { W = We1;            op = P;   }
    else if (g == 1) { W = We1 + 128 * H_; op = Q;   }
    else             { W = Wn1;            op = pre; }
    const int n  = t >> 5;
    const int c0 = (t & 31) * 4;
    __syncthreads();

    float4 r4 = colgemm128(W + c0, &act[n][0]);
    if (g == 0) {
        float4 bv = *(const float4*)(be1 + c0);
        r4.x += bv.x; r4.y += bv.y; r4.z += bv.z; r4.w += bv.w;
    } else if (g == 1) {
        float off = (mask[node0 + n] - 1.0f) * 1e30f;   // 0 if m=1, -1e30 if m=0
        r4.x += off; r4.y += off; r4.z += off; r4.w += off;
    } else {
        float4 bv = *(const float4*)(bn1 + c0);
        r4.x += bv.x; r4.y += bv.y; r4.z += bv.z; r4.w += bv.w;
    }
    *(float4*)(op + (size_t)(node0 + n) * H_ + c0) = r4;
}

// ---------------------------------------------------------------------------
// k2: S'[i][c] = (m_i/max(cnt,1)) * sum_j silu(P[i][c] + Q'[j][c] + d_ij*wd[c])
// (mask_j folded into Q' by k1; silu(-1e30) == -0)
// grid 512 (4 i/block), block 512: c=t&127, jq=t>>7. packed-f32 math.
// ---------------------------------------------------------------------------
__global__ __launch_bounds__(512) void k2(
    const float* __restrict__ P, const float* __restrict__ Q,
    const float* __restrict__ We1, const float* __restrict__ positions,
    const float* __restrict__ mask, float* __restrict__ S)
{
    __shared__ float dls[256][4];
    __shared__ float part[4][4][128];
    __shared__ float cs;
    const int t  = threadIdx.x;
    const int b  = blockIdx.x >> 6;
    const int i0 = (blockIdx.x & 63) * 4;

    {
        const int t2 = t & 255;
        const int half = t >> 8;
        const int il = t2 & 3;
        const int jb = t2 >> 2;
        const float* pb = positions + b * N_ * 3;
        const float pix = pb[(i0 + il) * 3 + 0];
        const float piy = pb[(i0 + il) * 3 + 1];
        const float piz = pb[(i0 + il) * 3 + 2];
        #pragma unroll
        for (int s = 0; s < 2; ++s) {
            int j = jb + 64 * (half * 2 + s);
            float dx = pix - pb[j * 3 + 0];
            float dy = piy - pb[j * 3 + 1];
            float dz = piz - pb[j * 3 + 2];
            float sq = dx * dx + dy * dy + dz * dz;
            dls[j][il] = (sq > 0.f) ? sqrtf(sq) : 0.f;
        }
    }
    __syncthreads();
    const int c  = t & 127;
    const int jq = t >> 7;
    const float wdc = We1[256 * H_ + c];
    const vf2 wd2 = {wdc, wdc};
    const vf2 b01 = {P[(size_t)(b * N_ + i0 + 0) * H_ + c],
                     P[(size_t)(b * N_ + i0 + 1) * H_ + c]};
    const vf2 b23 = {P[(size_t)(b * N_ + i0 + 2) * H_ + c],
                     P[(size_t)(b * N_ + i0 + 3) * H_ + c]};
    vf2 acc01 = {0.f, 0.f}, acc23 = {0.f, 0.f};
    const float* __restrict__ Qb = Q + (size_t)(b * N_ + jq * 64) * H_ + c;

    float qA[8], qB[8];
    #pragma unroll
    for (int u = 0; u < 8; ++u) qA[u] = Qb[u * H_];

    #pragma unroll
    for (int jj = 0; jj < 64; jj += 16) {
        #pragma unroll
        for (int u = 0; u < 8; ++u) qB[u] = Qb[(jj + 8 + u) * H_];
        #pragma unroll
        for (int u = 0; u < 8; ++u) {
            const int j = jq * 64 + jj + u;
            float4 d4 = *(const float4*)(&dls[j][0]);
            vf2 q2 = {qA[u], qA[u]};
            vf2 d01 = {d4.x, d4.y}, d23 = {d4.z, d4.w};
            vf2 x01 = __builtin_elementwise_fma(d01, wd2, b01 + q2);
            vf2 x23 = __builtin_elementwise_fma(d23, wd2, b23 + q2);
            vf2 e01 = {__expf(-x01.x), __expf(-x01.y)};
            vf2 e23 = {__expf(-x23.x), __expf(-x23.y)};
            vf2 den01 = e01 + 1.0f, den23 = e23 + 1.0f;
            vf2 r01 = {__builtin_amdgcn_rcpf(den01.x), __builtin_amdgcn_rcpf(den01.y)};
            vf2 r23 = {__builtin_amdgcn_rcpf(den23.x), __builtin_amdgcn_rcpf(den23.y)};
            acc01 = __builtin_elementwise_fma(x01, r01, acc01);
            acc23 = __builtin_elementwise_fma(x23, r23, acc23);
        }
        if (jj + 16 < 64) {
            #pragma unroll
            for (int u = 0; u < 8; ++u) qA[u] = Qb[(jj + 16 + u) * H_];
        }
        #pragma unroll
        for (int u = 0; u < 8; ++u) {
            const int j = jq * 64 + jj + 8 + u;
            float4 d4 = *(const float4*)(&dls[j][0]);
            vf2 q2 = {qB[u], qB[u]};
            vf2 d01 = {d4.x, d4.y}, d23 = {d4.z, d4.w};
            vf2 x01 = __builtin_elementwise_fma(d01, wd2, b01 + q2);
            vf2 x23 = __builtin_elementwise_fma(d23, wd2, b23 + q2);
            vf2 e01 = {__expf(-x01.x), __expf(-x01.y)};
            vf2 e23 = {__expf(-x23.x), __expf(-x23.y)};
            vf2 den01 = e01 + 1.0f, den23 = e23 + 1.0f;
            vf2 r01 = {__builtin_amdgcn_rcpf(den01.x), __builtin_amdgcn_rcpf(den01.y)};
            vf2 r23 = {__builtin_amdgcn_rcpf(den23.x), __builtin_amdgcn_rcpf(den23.y)};
            acc01 = __builtin_elementwise_fma(x01, r01, acc01);
            acc23 = __builtin_elementwise_fma(x23, r23, acc23);
        }
    }
    part[jq][0][c] = acc01.x; part[jq][1][c] = acc01.y;
    part[jq][2][c] = acc23.x; part[jq][3][c] = acc23.y;
    if (t < 64) {   // cnt = sum_j mask[b][j], first wave
        float mv = mask[b * N_ + t] + mask[b * N_ + 64 + t]
                 + mask[b * N_ + 128 + t] + mask[b * N_ + 192 + t];
        #pragma unroll
        for (int off = 32; off >= 1; off >>= 1) mv += __shfl_down(mv, off);
        if (t == 0) cs = mv;
    }
    __syncthreads();
    {
        const float inv_cnt = __builtin_amdgcn_rcpf(fmaxf(cs, 1.0f));
        const int il = t >> 7;
        const int cc = t & 127;
        const float mi = mask[b * N_ + i0 + il];
        S[(size_t)(b * N_ + i0 + il) * H_ + cc] = (mi * inv_cnt) *
            ((part[0][il][cc] + part[1][il][cc]) + (part[2][il][cc] + part[3][il][cc]));
    }
}

// ---------------------------------------------------------------------------
// kB: hidden = silu(pre + S'@W' + m_i*b')
// grid 512 (4-node tiles), block 128.
// ---------------------------------------------------------------------------
__global__ __launch_bounds__(128, 3) void kB(
    const float* __restrict__ S, const float* __restrict__ pre,
    const float* __restrict__ Wp, const float* __restrict__ bp,
    const float* __restrict__ mask, float* __restrict__ hidden)
{
    __shared__ float act[4][128];
    const int t = threadIdx.x;
    const int node0 = blockIdx.x * 4;
    {
        int r = t >> 5, col = (t * 4) & 127;
        *(float4*)(&act[r][col]) = *(const float4*)(S + (size_t)(node0 + r) * H_ + col);
    }
    const int n  = t >> 5;
    const int c0 = (t & 31) * 4;
    __syncthreads();
    float4 a = colgemm128(Wp + c0, &act[n][0]);
    const float mi = mask[node0 + n];
    float4 p4 = *(const float4*)(pre + (size_t)(node0 + n) * H_ + c0);
    float4 bv = *(const float4*)(bp + c0);
    float4 h;
    h.x = silu_fast(p4.x + a.x + mi * bv.x);
    h.y = silu_fast(p4.y + a.y + mi * bv.y);
    h.z = silu_fast(p4.z + a.z + mi * bv.z);
    h.w = silu_fast(p4.w + a.w + mi * bv.w);
    *(float4*)(hidden + (size_t)(node0 + n) * H_ + c0) = h;
}

// ---------------------------------------------------------------------------
// kC: out = node + m_i*(hidden@Wn2 + bn2)
// ---------------------------------------------------------------------------
__global__ __launch_bounds__(128, 3) void kC(
    const float* __restrict__ hidden, const float* __restrict__ node,
    const float* __restrict__ Wn2, const float* __restrict__ bn2,
    const float* __restrict__ mask, float* __restrict__ out)
{
    __shared__ float act[4][128];
    const int t = threadIdx.x;
    const int node0 = blockIdx.x * 4;
    {
        int r = t >> 5, col = (t * 4) & 127;
        *(float4*)(&act[r][col]) = *(const float4*)(hidden + (size_t)(node0 + r) * H_ + col);
    }
    const int n  = t >> 5;
    const int c0 = (t & 31) * 4;
    __syncthreads();
    float4 a = colgemm128(Wn2 + c0, &act[n][0]);
    const float mi = mask[node0 + n];
    float4 n4 = *(const float4*)(node + (size_t)(node0 + n) * H_ + c0);
    float4 bv = *(const float4*)(bn2 + c0);
    float4 r4;
    r4.x = n4.x + mi * (a.x + bv.x);
    r4.y = n4.y + mi * (a.y + bv.y);
    r4.z = n4.z + mi * (a.z + bv.z);
    r4.w = n4.w + mi * (a.w + bv.w);
    *(float4*)(out + (size_t)(node0 + n) * H_ + c0) = r4;
}

extern "C" void kernel_launch(void* const* d_in, const int* in_sizes, int n_in,
                              void* d_out, int out_size, void* d_ws, size_t ws_size,
                              hipStream_t stream)
{
    const float* node      = (const float*)d_in[0];
    const float* positions = (const float*)d_in[1];
    const float* mask      = (const float*)d_in[2];
    const float* We1       = (const float*)d_in[3];
    const float* be1       = (const float*)d_in[4];
    const float* We2       = (const float*)d_in[5];
    const float* be2       = (const float*)d_in[6];
    const float* Wn1       = (const float*)d_in[7];
    const float* bn1       = (const float*)d_in[8];
    const float* Wn2       = (const float*)d_in[9];
    const float* bn2       = (const float*)d_in[10];
    float* out = (float*)d_out;

    const size_t SZ = (size_t)NODES_ * H_;     // 1 MB each
    float* P      = (float*)d_ws;
    float* Q      = P + SZ;
    float* pre    = Q + SZ;
    float* S      = pre + SZ;
    float* Wp     = S + SZ;                    // 128x128 = 64 KB
    float* bp     = Wp + H_ * H_;              // 128 floats
    float* hidden = P;                         // reuse (P dead after k2)

    k0_fold<<<129,  128, 0, stream>>>(We2, be2, Wn1, Wp, bp);
    k1     <<<1536, 128, 0, stream>>>(node, We1, be1, Wn1, bn1, mask, P, Q, pre);
    k2     <<<512,  512, 0, stream>>>(P, Q, We1, positions, mask, S);
    kB     <<<512,  128, 0, stream>>>(S, pre, Wp, bp, mask, hidden);
    kC     <<<512,  128, 0, stream>>>(hidden, node, Wn2, bn2, mask, out);
}

// Round 5
// 199.009 us; speedup vs baseline: 1.7881x; 1.7881x over previous
//
#include <hip/hip_runtime.h>
#include <hip/hip_bf16.h>
#include <math.h>

#define B_ 8
#define N_ 256
#define H_ 128
#define NODES_ (B_ * N_)   // 2048

typedef float vf2 __attribute__((ext_vector_type(2)));

__device__ __forceinline__ float silu_fast(float x) {
    float e = __expf(-x);
    return x * __builtin_amdgcn_rcpf(1.0f + e);
}

// K=128 column-GEMM inner: thread owns 4 output columns; weights at Wc
// (pre-offset by c0, row stride H_); activations arow[] in LDS (broadcast).
// Depth-4 float4 ping-pong: 32 weight VGPRs in flight — fits without spill
// (R4 lesson: depth-8 = 64 VGPRs spilled to scratch, 575 MB HBM traffic).
__device__ __forceinline__ float4 colgemm4(const float* __restrict__ Wc,
                                           const float* __restrict__ arow)
{
    float4 wA[4], wB[4];
    #pragma unroll
    for (int u = 0; u < 4; ++u) wA[u] = *(const float4*)(Wc + u * H_);
    float4 a = {0.f,0.f,0.f,0.f}, b = {0.f,0.f,0.f,0.f};
    #pragma unroll
    for (int k = 0; k < 128; k += 8) {
        #pragma unroll
        for (int u = 0; u < 4; ++u) wB[u] = *(const float4*)(Wc + (k + 4 + u) * H_);
        #pragma unroll
        for (int u = 0; u < 4; u += 2) {
            float v0 = arow[k + u], v1 = arow[k + u + 1];
            a.x = fmaf(v0, wA[u].x, a.x);   a.y = fmaf(v0, wA[u].y, a.y);
            a.z = fmaf(v0, wA[u].z, a.z);   a.w = fmaf(v0, wA[u].w, a.w);
            b.x = fmaf(v1, wA[u+1].x, b.x); b.y = fmaf(v1, wA[u+1].y, b.y);
            b.z = fmaf(v1, wA[u+1].z, b.z); b.w = fmaf(v1, wA[u+1].w, b.w);
        }
        if (k + 8 < 128) {
            #pragma unroll
            for (int u = 0; u < 4; ++u) wA[u] = *(const float4*)(Wc + (k + 8 + u) * H_);
        }
        #pragma unroll
        for (int u = 0; u < 4; u += 2) {
            float v0 = arow[k + 4 + u], v1 = arow[k + 4 + u + 1];
            a.x = fmaf(v0, wB[u].x, a.x);   a.y = fmaf(v0, wB[u].y, a.y);
            a.z = fmaf(v0, wB[u].z, a.z);   a.w = fmaf(v0, wB[u].w, a.w);
            b.x = fmaf(v1, wB[u+1].x, b.x); b.y = fmaf(v1, wB[u+1].y, b.y);
            b.z = fmaf(v1, wB[u+1].z, b.z); b.w = fmaf(v1, wB[u+1].w, b.w);
        }
    }
    float4 r; r.x = a.x + b.x; r.y = a.y + b.y; r.z = a.z + b.z; r.w = a.w + b.w;
    return r;
}

// ---------------------------------------------------------------------------
// k1: g=0: P = node@We1a + be1
//     g=1: Q = node@We1b + (m_j-1)*1e30   (mask folded: silu -> -0)
//     g=2: pre = node@Wn1a + bn1
//     block 768 (g=3): bp = be2@Wn1b      (128 floats, piggybacked)
// grid 769, block 256: 8 nodes/block, n = t>>5, c0 = (t&31)*4.
// ---------------------------------------------------------------------------
__global__ __launch_bounds__(256) void k1(
    const float* __restrict__ node, const float* __restrict__ We1,
    const float* __restrict__ be1, const float* __restrict__ Wn1,
    const float* __restrict__ bn1, const float* __restrict__ mask,
    const float* __restrict__ be2,
    float* __restrict__ P, float* __restrict__ Q, float* __restrict__ pre,
    float* __restrict__ bp)
{
    __shared__ float act[8][128];
    const int t = threadIdx.x;
    const int g = blockIdx.x >> 8;

    if (g == 3) {                       // bp = be2 @ Wn1[128:,:]
        if (t < 128) act[0][t] = be2[t];
        __syncthreads();
        if (t < 32) {
            const int c0 = t * 4;
            float4 r4 = colgemm4(Wn1 + 128 * H_ + c0, &act[0][0]);
            *(float4*)(bp + c0) = r4;
        }
        return;
    }

    const int node0 = (blockIdx.x & 255) * 8;
    {
        int idx = t * 4;
        int r = idx >> 7, col = idx & 127;
        *(float4*)(&act[r][col]) = *(const float4*)(node + (size_t)(node0 + r) * H_ + col);
    }
    const float* W; float* op;
    if (g == 0)      { W = We1;            op = P;   }
    else if (g == 1) { W = We1 + 128 * H_; op = Q;   }
    else             { W = Wn1;            op = pre; }
    const int n  = t >> 5;
    const int c0 = (t & 31) * 4;
    __syncthreads();

    float4 r4 = colgemm4(W + c0, &act[n][0]);
    if (g == 0) {
        float4 bv = *(const float4*)(be1 + c0);
        r4.x += bv.x; r4.y += bv.y; r4.z += bv.z; r4.w += bv.w;
    } else if (g == 1) {
        float off = (mask[node0 + n] - 1.0f) * 1e30f;   // 0 if m=1, -1e30 if m=0
        r4.x += off; r4.y += off; r4.z += off; r4.w += off;
    } else {
        float4 bv = *(const float4*)(bn1 + c0);
        r4.x += bv.x; r4.y += bv.y; r4.z += bv.z; r4.w += bv.w;
    }
    *(float4*)(op + (size_t)(node0 + n) * H_ + c0) = r4;
}

// ---------------------------------------------------------------------------
// k2: S'[i][c] = (m_i/max(cnt,1)) * sum_j silu(P[i][c] + Q'[j][c] + d_ij*wd[c])
// grid 512 (4 i/block), block 512: c=t&127, jq=t>>7. Transcendental-bound.
// ---------------------------------------------------------------------------
__global__ __launch_bounds__(512) void k2(
    const float* __restrict__ P, const float* __restrict__ Q,
    const float* __restrict__ We1, const float* __restrict__ positions,
    const float* __restrict__ mask, float* __restrict__ S)
{
    __shared__ float dls[256][4];
    __shared__ float part[4][4][128];
    __shared__ float cs;
    const int t  = threadIdx.x;
    const int b  = blockIdx.x >> 6;
    const int i0 = (blockIdx.x & 63) * 4;

    {
        const int t2 = t & 255;
        const int half = t >> 8;
        const int il = t2 & 3;
        const int jb = t2 >> 2;
        const float* pb = positions + b * N_ * 3;
        const float pix = pb[(i0 + il) * 3 + 0];
        const float piy = pb[(i0 + il) * 3 + 1];
        const float piz = pb[(i0 + il) * 3 + 2];
        #pragma unroll
        for (int s = 0; s < 2; ++s) {
            int j = jb + 64 * (half * 2 + s);
            float dx = pix - pb[j * 3 + 0];
            float dy = piy - pb[j * 3 + 1];
            float dz = piz - pb[j * 3 + 2];
            float sq = dx * dx + dy * dy + dz * dz;
            dls[j][il] = (sq > 0.f) ? sqrtf(sq) : 0.f;
        }
    }
    __syncthreads();
    const int c  = t & 127;
    const int jq = t >> 7;
    const float wdc = We1[256 * H_ + c];
    const vf2 wd2 = {wdc, wdc};
    const vf2 b01 = {P[(size_t)(b * N_ + i0 + 0) * H_ + c],
                     P[(size_t)(b * N_ + i0 + 1) * H_ + c]};
    const vf2 b23 = {P[(size_t)(b * N_ + i0 + 2) * H_ + c],
                     P[(size_t)(b * N_ + i0 + 3) * H_ + c]};
    vf2 acc01 = {0.f, 0.f}, acc23 = {0.f, 0.f};
    const float* __restrict__ Qb = Q + (size_t)(b * N_ + jq * 64) * H_ + c;

    float qA[8], qB[8];
    #pragma unroll
    for (int u = 0; u < 8; ++u) qA[u] = Qb[u * H_];

    #pragma unroll
    for (int jj = 0; jj < 64; jj += 16) {
        #pragma unroll
        for (int u = 0; u < 8; ++u) qB[u] = Qb[(jj + 8 + u) * H_];
        #pragma unroll
        for (int u = 0; u < 8; ++u) {
            const int j = jq * 64 + jj + u;
            float4 d4 = *(const float4*)(&dls[j][0]);
            vf2 q2 = {qA[u], qA[u]};
            vf2 d01 = {d4.x, d4.y}, d23 = {d4.z, d4.w};
            vf2 x01 = __builtin_elementwise_fma(d01, wd2, b01 + q2);
            vf2 x23 = __builtin_elementwise_fma(d23, wd2, b23 + q2);
            vf2 e01 = {__expf(-x01.x), __expf(-x01.y)};
            vf2 e23 = {__expf(-x23.x), __expf(-x23.y)};
            vf2 den01 = e01 + 1.0f, den23 = e23 + 1.0f;
            vf2 r01 = {__builtin_amdgcn_rcpf(den01.x), __builtin_amdgcn_rcpf(den01.y)};
            vf2 r23 = {__builtin_amdgcn_rcpf(den23.x), __builtin_amdgcn_rcpf(den23.y)};
            acc01 = __builtin_elementwise_fma(x01, r01, acc01);
            acc23 = __builtin_elementwise_fma(x23, r23, acc23);
        }
        if (jj + 16 < 64) {
            #pragma unroll
            for (int u = 0; u < 8; ++u) qA[u] = Qb[(jj + 16 + u) * H_];
        }
        #pragma unroll
        for (int u = 0; u < 8; ++u) {
            const int j = jq * 64 + jj + 8 + u;
            float4 d4 = *(const float4*)(&dls[j][0]);
            vf2 q2 = {qB[u], qB[u]};
            vf2 d01 = {d4.x, d4.y}, d23 = {d4.z, d4.w};
            vf2 x01 = __builtin_elementwise_fma(d01, wd2, b01 + q2);
            vf2 x23 = __builtin_elementwise_fma(d23, wd2, b23 + q2);
            vf2 e01 = {__expf(-x01.x), __expf(-x01.y)};
            vf2 e23 = {__expf(-x23.x), __expf(-x23.y)};
            vf2 den01 = e01 + 1.0f, den23 = e23 + 1.0f;
            vf2 r01 = {__builtin_amdgcn_rcpf(den01.x), __builtin_amdgcn_rcpf(den01.y)};
            vf2 r23 = {__builtin_amdgcn_rcpf(den23.x), __builtin_amdgcn_rcpf(den23.y)};
            acc01 = __builtin_elementwise_fma(x01, r01, acc01);
            acc23 = __builtin_elementwise_fma(x23, r23, acc23);
        }
    }
    part[jq][0][c] = acc01.x; part[jq][1][c] = acc01.y;
    part[jq][2][c] = acc23.x; part[jq][3][c] = acc23.y;
    if (t < 64) {
        float mv = mask[b * N_ + t] + mask[b * N_ + 64 + t]
                 + mask[b * N_ + 128 + t] + mask[b * N_ + 192 + t];
        #pragma unroll
        for (int off = 32; off >= 1; off >>= 1) mv += __shfl_down(mv, off);
        if (t == 0) cs = mv;
    }
    __syncthreads();
    {
        const float inv_cnt = __builtin_amdgcn_rcpf(fmaxf(cs, 1.0f));
        const int il = t >> 7;
        const int cc = t & 127;
        const float mi = mask[b * N_ + i0 + il];
        S[(size_t)(b * N_ + i0 + il) * H_ + cc] = (mi * inv_cnt) *
            ((part[0][il][cc] + part[1][il][cc]) + (part[2][il][cc] + part[3][il][cc]));
    }
}

// ---------------------------------------------------------------------------
// kBC: fused node epilogue, 3 chained GEMMs through LDS:
//   T      = S' @ We2
//   hidden = silu(pre + T @ Wn1[128:] + m_i*bp)
//   out    = node + m_i * (hidden @ Wn2 + bn2)
// grid 256 (8 nodes/block), block 256: n = t>>5, c0 = (t&31)*4.
// ---------------------------------------------------------------------------
__global__ __launch_bounds__(256) void kBC(
    const float* __restrict__ S, const float* __restrict__ pre,
    const float* __restrict__ node, const float* __restrict__ mask,
    const float* __restrict__ We2, const float* __restrict__ Wn1,
    const float* __restrict__ Wn2, const float* __restrict__ bn2,
    const float* __restrict__ bp, float* __restrict__ out)
{
    __shared__ float A[8][128], T[8][128];
    const int t = threadIdx.x;
    const int node0 = blockIdx.x * 8;
    {
        int idx = t * 4;
        int r = idx >> 7, col = idx & 127;
        *(float4*)(&A[r][col]) = *(const float4*)(S + (size_t)(node0 + r) * H_ + col);
    }
    const int n  = t >> 5;
    const int c0 = (t & 31) * 4;
    __syncthreads();

    // phase 1: T = S' @ We2
    float4 x = colgemm4(We2 + c0, &A[n][0]);
    *(float4*)(&T[n][c0]) = x;
    __syncthreads();

    // phase 2: hidden = silu(pre + T @ Wn1b + mi*bp)
    float4 y = colgemm4(Wn1 + 128 * H_ + c0, &T[n][0]);
    const float mi = mask[node0 + n];
    float4 p4  = *(const float4*)(pre + (size_t)(node0 + n) * H_ + c0);
    float4 bpv = *(const float4*)(bp + c0);
    float4 h;
    h.x = silu_fast(fmaf(mi, bpv.x, p4.x + y.x));
    h.y = silu_fast(fmaf(mi, bpv.y, p4.y + y.y));
    h.z = silu_fast(fmaf(mi, bpv.z, p4.z + y.z));
    h.w = silu_fast(fmaf(mi, bpv.w, p4.w + y.w));
    *(float4*)(&A[n][c0]) = h;       // A reads all completed at first sync
    __syncthreads();

    // phase 3: out = node + mi * (hidden @ Wn2 + bn2)
    float4 z = colgemm4(Wn2 + c0, &A[n][0]);
    float4 n4 = *(const float4*)(node + (size_t)(node0 + n) * H_ + c0);
    float4 bv = *(const float4*)(bn2 + c0);
    float4 r4;
    r4.x = n4.x + mi * (z.x + bv.x);
    r4.y = n4.y + mi * (z.y + bv.y);
    r4.z = n4.z + mi * (z.z + bv.z);
    r4.w = n4.w + mi * (z.w + bv.w);
    *(float4*)(out + (size_t)(node0 + n) * H_ + c0) = r4;
}

extern "C" void kernel_launch(void* const* d_in, const int* in_sizes, int n_in,
                              void* d_out, int out_size, void* d_ws, size_t ws_size,
                              hipStream_t stream)
{
    const float* node      = (const float*)d_in[0];
    const float* positions = (const float*)d_in[1];
    const float* mask      = (const float*)d_in[2];
    const float* We1       = (const float*)d_in[3];
    const float* be1       = (const float*)d_in[4];
    const float* We2       = (const float*)d_in[5];
    const float* be2       = (const float*)d_in[6];
    const float* Wn1       = (const float*)d_in[7];
    const float* bn1       = (const float*)d_in[8];
    const float* Wn2       = (const float*)d_in[9];
    const float* bn2       = (const float*)d_in[10];
    float* out = (float*)d_out;

    const size_t SZ = (size_t)NODES_ * H_;     // 1 MB each
    float* P   = (float*)d_ws;
    float* Q   = P + SZ;
    float* pre = Q + SZ;
    float* S   = pre + SZ;
    float* bp  = S + SZ;                       // 128 floats

    k1 <<<769, 256, 0, stream>>>(node, We1, be1, Wn1, bn1, mask, be2, P, Q, pre, bp);
    k2 <<<512, 512, 0, stream>>>(P, Q, We1, positions, mask, S);
    kBC<<<256, 256, 0, stream>>>(S, pre, node, mask, We2, Wn1, Wn2, bn2, bp, out);
}

// Round 6
// 122.477 us; speedup vs baseline: 2.9054x; 1.6249x over previous
//
#include <hip/hip_runtime.h>
#include <hip/hip_bf16.h>
#include <math.h>

#define B_ 8
#define N_ 256
#define H_ 128
#define NODES_ (B_ * N_)   // 2048

typedef float vf2 __attribute__((ext_vector_type(2)));

__device__ __forceinline__ float silu_fast(float x) {
    float e = __expf(-x);
    return x * __builtin_amdgcn_rcpf(1.0f + e);
}

// K=128 column-GEMM: thread owns 4 output columns (Wc pre-offset by c0, row
// stride H_); activations arow[] in LDS (wave-broadcast reads).
// FLAT unroll-8 loop: compiler clumps the 8 independent float4 loads per
// window and schedules waitcnt itself. ~32 transient load VGPRs — allocator-
// safe at multiple inline sites (R4/R5 lesson: manual deep ping-pong spilled,
// VGPR=256, 100+ MB scratch traffic).
__device__ __forceinline__ float4 cg128(const float* __restrict__ Wc,
                                        const float* __restrict__ arow)
{
    float4 acc = {0.f, 0.f, 0.f, 0.f};
    #pragma unroll 8
    for (int k = 0; k < 128; ++k) {
        float4 w = *(const float4*)(Wc + k * H_);
        float v  = arow[k];
        acc.x = fmaf(v, w.x, acc.x);
        acc.y = fmaf(v, w.y, acc.y);
        acc.z = fmaf(v, w.z, acc.z);
        acc.w = fmaf(v, w.w, acc.w);
    }
    return acc;
}

// ---------------------------------------------------------------------------
// k1: g=0: P = node@We1a + be1
//     g=1: Q = node@We1b + (m_j-1)*1e30   (mask_j folded: silu -> -0)
//     g=2: pre = node@Wn1a + bn1
// grid 768, block 256: 8 nodes/block, n = t>>5, c0 = (t&31)*4.
// ---------------------------------------------------------------------------
__global__ __launch_bounds__(256) void k1(
    const float* __restrict__ node, const float* __restrict__ We1,
    const float* __restrict__ be1, const float* __restrict__ Wn1,
    const float* __restrict__ bn1, const float* __restrict__ mask,
    float* __restrict__ P, float* __restrict__ Q, float* __restrict__ pre)
{
    __shared__ float act[8][128];
    const int t = threadIdx.x;
    const int g = blockIdx.x >> 8;               // 0:P 1:Q 2:pre
    const int node0 = (blockIdx.x & 255) * 8;
    {
        int idx = t * 4;
        int r = idx >> 7, col = idx & 127;
        *(float4*)(&act[r][col]) = *(const float4*)(node + (size_t)(node0 + r) * H_ + col);
    }
    const float* W; float* op;
    if (g == 0)      { W = We1;            op = P;   }
    else if (g == 1) { W = We1 + 128 * H_; op = Q;   }
    else             { W = Wn1;            op = pre; }
    const int n  = t >> 5;
    const int c0 = (t & 31) * 4;
    __syncthreads();

    float4 r4 = cg128(W + c0, &act[n][0]);
    if (g == 0) {
        float4 bv = *(const float4*)(be1 + c0);
        r4.x += bv.x; r4.y += bv.y; r4.z += bv.z; r4.w += bv.w;
    } else if (g == 1) {
        float off = (mask[node0 + n] - 1.0f) * 1e30f;   // 0 if m=1, -1e30 if m=0
        r4.x += off; r4.y += off; r4.z += off; r4.w += off;
    } else {
        float4 bv = *(const float4*)(bn1 + c0);
        r4.x += bv.x; r4.y += bv.y; r4.z += bv.z; r4.w += bv.w;
    }
    *(float4*)(op + (size_t)(node0 + n) * H_ + c0) = r4;
}

// ---------------------------------------------------------------------------
// k2: S'[i][c] = (m_i/max(cnt,1)) * sum_j silu(P[i][c] + Q'[j][c] + d_ij*wd[c])
// grid 512 (4 i/block), block 512: c = t&127, j-quarter jq = t>>7.
// Flat unroll-8 j-loop: 8 Q loads clumped per window by the compiler.
// ---------------------------------------------------------------------------
__global__ __launch_bounds__(512) void k2(
    const float* __restrict__ P, const float* __restrict__ Q,
    const float* __restrict__ We1, const float* __restrict__ positions,
    const float* __restrict__ mask, float* __restrict__ S)
{
    __shared__ float dls[256][4];
    __shared__ float part[4][4][128];
    __shared__ float cs;
    const int t  = threadIdx.x;
    const int b  = blockIdx.x >> 6;
    const int i0 = (blockIdx.x & 63) * 4;

    {
        const int t2 = t & 255;
        const int half = t >> 8;
        const int il = t2 & 3;
        const int jb = t2 >> 2;
        const float* pb = positions + b * N_ * 3;
        const float pix = pb[(i0 + il) * 3 + 0];
        const float piy = pb[(i0 + il) * 3 + 1];
        const float piz = pb[(i0 + il) * 3 + 2];
        #pragma unroll
        for (int s = 0; s < 2; ++s) {
            int j = jb + 64 * (half * 2 + s);
            float dx = pix - pb[j * 3 + 0];
            float dy = piy - pb[j * 3 + 1];
            float dz = piz - pb[j * 3 + 2];
            float sq = dx * dx + dy * dy + dz * dz;
            dls[j][il] = (sq > 0.f) ? sqrtf(sq) : 0.f;
        }
    }
    __syncthreads();
    const int c  = t & 127;
    const int jq = t >> 7;
    const float wdc = We1[256 * H_ + c];
    const vf2 wd2 = {wdc, wdc};
    const vf2 b01 = {P[(size_t)(b * N_ + i0 + 0) * H_ + c],
                     P[(size_t)(b * N_ + i0 + 1) * H_ + c]};
    const vf2 b23 = {P[(size_t)(b * N_ + i0 + 2) * H_ + c],
                     P[(size_t)(b * N_ + i0 + 3) * H_ + c]};
    vf2 acc01 = {0.f, 0.f}, acc23 = {0.f, 0.f};
    const float* __restrict__ Qb = Q + (size_t)(b * N_ + jq * 64) * H_ + c;

    #pragma unroll 8
    for (int jj = 0; jj < 64; ++jj) {
        const float q = Qb[jj * H_];
        const int j = jq * 64 + jj;
        float4 d4 = *(const float4*)(&dls[j][0]);
        vf2 q2 = {q, q};
        vf2 d01 = {d4.x, d4.y}, d23 = {d4.z, d4.w};
        vf2 x01 = __builtin_elementwise_fma(d01, wd2, b01 + q2);
        vf2 x23 = __builtin_elementwise_fma(d23, wd2, b23 + q2);
        vf2 e01 = {__expf(-x01.x), __expf(-x01.y)};
        vf2 e23 = {__expf(-x23.x), __expf(-x23.y)};
        vf2 den01 = e01 + 1.0f, den23 = e23 + 1.0f;
        vf2 r01 = {__builtin_amdgcn_rcpf(den01.x), __builtin_amdgcn_rcpf(den01.y)};
        vf2 r23 = {__builtin_amdgcn_rcpf(den23.x), __builtin_amdgcn_rcpf(den23.y)};
        acc01 = __builtin_elementwise_fma(x01, r01, acc01);
        acc23 = __builtin_elementwise_fma(x23, r23, acc23);
    }
    part[jq][0][c] = acc01.x; part[jq][1][c] = acc01.y;
    part[jq][2][c] = acc23.x; part[jq][3][c] = acc23.y;
    if (t < 64) {
        float mv = mask[b * N_ + t] + mask[b * N_ + 64 + t]
                 + mask[b * N_ + 128 + t] + mask[b * N_ + 192 + t];
        #pragma unroll
        for (int off = 32; off >= 1; off >>= 1) mv += __shfl_down(mv, off);
        if (t == 0) cs = mv;
    }
    __syncthreads();
    {
        const float inv_cnt = __builtin_amdgcn_rcpf(fmaxf(cs, 1.0f));
        const int il = t >> 7;
        const int cc = t & 127;
        const float mi = mask[b * N_ + i0 + il];
        S[(size_t)(b * N_ + i0 + il) * H_ + cc] = (mi * inv_cnt) *
            ((part[0][il][cc] + part[1][il][cc]) + (part[2][il][cc] + part[3][il][cc]));
    }
}

// ---------------------------------------------------------------------------
// kBC: fused node epilogue, 3 chained GEMMs through LDS:
//   T      = S' @ We2 + m_i*be2          (be2 fold: (T+mi*be2)@Wn1b ==
//   hidden = silu(pre + T @ Wn1[128:])    T@Wn1b + mi*(be2@Wn1b))
//   out    = node + m_i * (hidden @ Wn2 + bn2)
// grid 512 (4 nodes/block), block 128: n = t>>5, c0 = (t&31)*4.
// ---------------------------------------------------------------------------
__global__ __launch_bounds__(128) void kBC(
    const float* __restrict__ S, const float* __restrict__ pre,
    const float* __restrict__ node, const float* __restrict__ mask,
    const float* __restrict__ We2, const float* __restrict__ be2,
    const float* __restrict__ Wn1, const float* __restrict__ Wn2,
    const float* __restrict__ bn2, float* __restrict__ out)
{
    __shared__ float A[4][128], T[4][128];
    const int t = threadIdx.x;
    const int node0 = blockIdx.x * 4;
    {
        int idx = t * 4;
        int r = idx >> 7, col = idx & 127;
        *(float4*)(&A[r][col]) = *(const float4*)(S + (size_t)(node0 + r) * H_ + col);
    }
    const int n  = t >> 5;
    const int c0 = (t & 31) * 4;
    const float mi = mask[node0 + n];
    __syncthreads();

    // phase 1: T = S' @ We2 + mi*be2
    float4 x = cg128(We2 + c0, &A[n][0]);
    {
        float4 b2 = *(const float4*)(be2 + c0);
        x.x = fmaf(mi, b2.x, x.x); x.y = fmaf(mi, b2.y, x.y);
        x.z = fmaf(mi, b2.z, x.z); x.w = fmaf(mi, b2.w, x.w);
    }
    *(float4*)(&T[n][c0]) = x;
    __syncthreads();

    // phase 2: hidden = silu(pre + T @ Wn1b)
    float4 y = cg128(Wn1 + 128 * H_ + c0, &T[n][0]);
    float4 p4 = *(const float4*)(pre + (size_t)(node0 + n) * H_ + c0);
    float4 h;
    h.x = silu_fast(p4.x + y.x);
    h.y = silu_fast(p4.y + y.y);
    h.z = silu_fast(p4.z + y.z);
    h.w = silu_fast(p4.w + y.w);
    *(float4*)(&A[n][c0]) = h;
    __syncthreads();

    // phase 3: out = node + mi * (hidden @ Wn2 + bn2)
    float4 z = cg128(Wn2 + c0, &A[n][0]);
    float4 n4 = *(const float4*)(node + (size_t)(node0 + n) * H_ + c0);
    float4 bv = *(const float4*)(bn2 + c0);
    float4 r4;
    r4.x = n4.x + mi * (z.x + bv.x);
    r4.y = n4.y + mi * (z.y + bv.y);
    r4.z = n4.z + mi * (z.z + bv.z);
    r4.w = n4.w + mi * (z.w + bv.w);
    *(float4*)(out + (size_t)(node0 + n) * H_ + c0) = r4;
}

extern "C" void kernel_launch(void* const* d_in, const int* in_sizes, int n_in,
                              void* d_out, int out_size, void* d_ws, size_t ws_size,
                              hipStream_t stream)
{
    const float* node      = (const float*)d_in[0];
    const float* positions = (const float*)d_in[1];
    const float* mask      = (const float*)d_in[2];
    const float* We1       = (const float*)d_in[3];
    const float* be1       = (const float*)d_in[4];
    const float* We2       = (const float*)d_in[5];
    const float* be2       = (const float*)d_in[6];
    const float* Wn1       = (const float*)d_in[7];
    const float* bn1       = (const float*)d_in[8];
    const float* Wn2       = (const float*)d_in[9];
    const float* bn2       = (const float*)d_in[10];
    float* out = (float*)d_out;

    const size_t SZ = (size_t)NODES_ * H_;     // 1 MB each
    float* P   = (float*)d_ws;
    float* Q   = P + SZ;
    float* pre = Q + SZ;
    float* S   = pre + SZ;                     // peak ws = 4 MB

    k1 <<<768, 256, 0, stream>>>(node, We1, be1, Wn1, bn1, mask, P, Q, pre);
    k2 <<<512, 512, 0, stream>>>(P, Q, We1, positions, mask, S);
    kBC<<<512, 128, 0, stream>>>(S, pre, node, mask, We2, be2, Wn1, Wn2, bn2, out);
}